// Round 11
// baseline (417.122 us; speedup 1.0000x reference)
//
#include <hip/hip_runtime.h>
#include <hip/hip_bf16.h>
#include <stdint.h>

// GraphConv x2 — round 11: round-10 passing base + ONE change:
//   fill_kernel scatters pairs via u64 atomicExch (memory-side path, no 64B
//   line write-allocate — evidence: round-1 atomicAdd counters showed ~8B
//   writeback per 4B atomic vs ~64B per plain scattered store).
//   CSR by dst (proven). Per layer:
//     gemm:   xr = x @ Wrel^T (bf16);  io = x @ Wroot^T + b  (io==d_out, f32)
//     gather: io[i] = [relu]( sum_j w_j * xr[src_j] + io[i] )  in place, ILP-8
// N=100000, E=1600000, D=64

#define D 64
#define SCAN_CHUNK 1024

typedef unsigned int   u32;
typedef unsigned short u16;

__device__ __forceinline__ float bf2f(u16 v) {
    return __uint_as_float(((u32)v) << 16);
}
__device__ __forceinline__ u16 f2bf(float f) {
    u32 u = __float_as_uint(f);
    u32 r = (u + 0x7fffu + ((u >> 16) & 1u)) >> 16;   // round-to-nearest-even
    return (u16)r;
}

// ---------------- CSR build (proven structure) ----------------
__global__ __launch_bounds__(256) void hist_kernel(
    const int* __restrict__ ei, int* __restrict__ deg, int E_)
{
    int e = blockIdx.x * 256 + threadIdx.x;
    if (e >= E_) return;
    atomicAdd(&deg[ei[E_ + e]], 1);
}

__global__ __launch_bounds__(256) void scan1_kernel(
    const int* __restrict__ deg, int* __restrict__ loc, int* __restrict__ partial, int n)
{
    __shared__ int wsum[4];
    int t = threadIdx.x;
    int base = blockIdx.x * SCAN_CHUNK + t * 4;
    int v0 = (base + 0 < n) ? deg[base + 0] : 0;
    int v1 = (base + 1 < n) ? deg[base + 1] : 0;
    int v2 = (base + 2 < n) ? deg[base + 2] : 0;
    int v3 = (base + 3 < n) ? deg[base + 3] : 0;
    int s = v0 + v1 + v2 + v3;
    int lane = t & 63, wave = t >> 6;
    int inc = s;
    for (int off = 1; off < 64; off <<= 1) {
        int u = __shfl_up(inc, off);
        if (lane >= off) inc += u;
    }
    if (lane == 63) wsum[wave] = inc;
    __syncthreads();
    int woff = 0;
    for (int w = 0; w < wave; ++w) woff += wsum[w];
    int ex = woff + inc - s;
    if (base + 0 < n) loc[base + 0] = ex;
    if (base + 1 < n) loc[base + 1] = ex + v0;
    if (base + 2 < n) loc[base + 2] = ex + v0 + v1;
    if (base + 3 < n) loc[base + 3] = ex + v0 + v1 + v2;
    if (t == 255) partial[blockIdx.x] = woff + inc;
}

__global__ __launch_bounds__(1024) void scan2_kernel(int* __restrict__ partial, int nchunk)
{
    __shared__ int sd[1024];
    int t = threadIdx.x;
    if (t < nchunk) sd[t] = partial[t];
    __syncthreads();
    if (t == 0) {
        int run = 0;
        for (int i = 0; i < nchunk; ++i) { int v = sd[i]; sd[i] = run; run += v; }
    }
    __syncthreads();
    if (t < nchunk) partial[t] = sd[t];
}

__global__ __launch_bounds__(256) void scan3_kernel(
    int* __restrict__ rowptr, const int* __restrict__ partial,
    int* __restrict__ cursor, int n, int Etot)
{
    int i = blockIdx.x * 256 + threadIdx.x;
    if (i == 0) rowptr[n] = Etot;
    if (i >= n) return;
    int v = rowptr[i] + partial[i >> 10];
    rowptr[i] = v;
    cursor[i] = v;
}

__global__ __launch_bounds__(256) void fill_kernel(
    const int* __restrict__ ei, const float* __restrict__ ew,
    int* __restrict__ cursor, unsigned long long* __restrict__ pairs, int E_)
{
    int e = blockIdx.x * 256 + threadIdx.x;
    if (e >= E_) return;
    int src = ei[e];
    int dst = ei[E_ + e];
    int p = atomicAdd(&cursor[dst], 1);
    // low word = src, high word = weight bits (== float2{src_as_float, w} layout)
    unsigned long long packed =
        (unsigned long long)(u32)src | ((unsigned long long)__float_as_uint(ew[e]) << 32);
    // memory-side scatter: atomicExch avoids the 64B write-allocate per 8B store
    atomicExch(&pairs[p], packed);
}

// ---------------- pre-transform GEMM (round-6/9/10 proven; bf16 xr store) ----------------
// xr[i] = xin[i] @ Wrel^T (bf16);  io[i] = xin[i] @ Wroot^T + b (f32).
// xin MAY ALIAS io (layer 2) — each row read before same-row write, same wave.
#define GW 8   // waves/block (512 threads)
#define GR 4   // rows/wave
__global__ __launch_bounds__(512) void gemm_kernel(
    const float* xin,
    const float* __restrict__ Wrel, const float* __restrict__ brel,
    const float* __restrict__ Wroot,
    u16* __restrict__ xr, float* io, int Nn)
{
    __shared__ float WrelT[D][D + 1];   // WrelT[k][d] = Wrel[d*64+k]; pad kills conflicts
    __shared__ float WrootT[D][D + 1];
    __shared__ float bias[D];
    __shared__ float rowX[GW][GR][D];

    int tid = threadIdx.x;
    for (int i = tid; i < D * D; i += 512) {
        int d = i >> 6, k = i & 63;
        WrelT [k][d] = Wrel [i];
        WrootT[k][d] = Wroot[i];
    }
    if (tid < D) bias[tid] = brel[tid];
    __syncthreads();

    int wave = tid >> 6, lane = tid & 63;

    int base = (blockIdx.x * GW + wave) * GR;
    if (base >= Nn) return;             // wave-uniform, after barrier
    int nr = min(GR, Nn - base);

    for (int r = 0; r < nr; ++r)
        rowX[wave][r][lane] = xin[(size_t)(base + r) * D + lane];
    // same-wave LDS write->read (proven rounds 2/5/6/9/10)

    float aR[GR] = {0.f, 0.f, 0.f, 0.f};
    float aC[GR] = {0.f, 0.f, 0.f, 0.f};
#pragma unroll
    for (int k4 = 0; k4 < 16; ++k4) {
        float4 xv[GR];
#pragma unroll
        for (int r = 0; r < GR; ++r)
            xv[r] = *reinterpret_cast<const float4*>(&rowX[wave][r][k4 * 4]); // broadcast b128
#pragma unroll
        for (int kk = 0; kk < 4; ++kk) {
            float wr = WrelT [k4 * 4 + kk][lane];
            float wc = WrootT[k4 * 4 + kk][lane];
#pragma unroll
            for (int r = 0; r < GR; ++r) {
                float xk = (kk == 0) ? xv[r].x : (kk == 1) ? xv[r].y
                         : (kk == 2) ? xv[r].z : xv[r].w;
                aR[r] = fmaf(xk, wr, aR[r]);
                aC[r] = fmaf(xk, wc, aC[r]);
            }
        }
    }
    for (int r = 0; r < nr; ++r) {
        size_t o = (size_t)(base + r) * D + lane;
        xr[o] = f2bf(aR[r]);            // bf16 store (proven numerics)
        io[o] = aC[r] + bias[lane];
    }
}

// ---------------- gather: ILP-8, bf16 rows, zero-weight padded (round-10 verbatim) ----------------
#define AW 8
template <bool RELU>
__global__ __launch_bounds__(512) void gather_kernel(
    const u16* __restrict__ xr, const uint64_t* __restrict__ pairs,
    const int* __restrict__ rowptr, float* __restrict__ io, int Nn)
{
    int tid  = threadIdx.x;
    int wave = tid >> 6, lane = tid & 63;
    int i = blockIdx.x * AW + wave;
    if (i >= Nn) return;                       // wave-uniform

    int beg = rowptr[i], end = rowptr[i + 1];
    float acc = 0.f;
    for (int b = beg; b < end; b += 64) {
        int cnt = min(64, end - b);
        // lanes >= cnt carry (src=0, w=0): padded edges read row 0, add 0
        uint64_t pv = (lane < cnt) ? __builtin_nontemporal_load(&pairs[b + lane])
                                   : (uint64_t)0;
        int   ps = (int)(u32)pv;
        float wv = __uint_as_float((u32)(pv >> 32));
        for (int j = 0; j < cnt; j += 8) {     // 8 independent gathers in flight
            int   s0 = __shfl(ps, j + 0), s1 = __shfl(ps, j + 1);
            int   s2 = __shfl(ps, j + 2), s3 = __shfl(ps, j + 3);
            int   s4 = __shfl(ps, j + 4), s5 = __shfl(ps, j + 5);
            int   s6 = __shfl(ps, j + 6), s7 = __shfl(ps, j + 7);
            float w0 = __shfl(wv, j + 0), w1 = __shfl(wv, j + 1);
            float w2 = __shfl(wv, j + 2), w3 = __shfl(wv, j + 3);
            float w4 = __shfl(wv, j + 4), w5 = __shfl(wv, j + 5);
            float w6 = __shfl(wv, j + 6), w7 = __shfl(wv, j + 7);
            float v0 = bf2f(xr[(size_t)s0 * D + lane]);
            float v1 = bf2f(xr[(size_t)s1 * D + lane]);
            float v2 = bf2f(xr[(size_t)s2 * D + lane]);
            float v3 = bf2f(xr[(size_t)s3 * D + lane]);
            float v4 = bf2f(xr[(size_t)s4 * D + lane]);
            float v5 = bf2f(xr[(size_t)s5 * D + lane]);
            float v6 = bf2f(xr[(size_t)s6 * D + lane]);
            float v7 = bf2f(xr[(size_t)s7 * D + lane]);
            acc = fmaf(v0, w0, acc); acc = fmaf(v1, w1, acc);
            acc = fmaf(v2, w2, acc); acc = fmaf(v3, w3, acc);
            acc = fmaf(v4, w4, acc); acc = fmaf(v5, w5, acc);
            acc = fmaf(v6, w6, acc); acc = fmaf(v7, w7, acc);
        }
    }
    size_t o = (size_t)i * D + lane;
    float v = acc + io[o];
    io[o] = RELU ? fmaxf(v, 0.f) : v;
}

extern "C" void kernel_launch(void* const* d_in, const int* in_sizes, int n_in,
                              void* d_out, int out_size, void* d_ws, size_t ws_size,
                              hipStream_t stream)
{
    const float* x      = (const float*)d_in[0];
    const int*   ei     = (const int*)  d_in[1];
    const float* ew     = (const float*)d_in[2];
    const float* Wrel1  = (const float*)d_in[3];
    const float* brel1  = (const float*)d_in[4];
    const float* Wroot1 = (const float*)d_in[5];
    const float* Wrel2  = (const float*)d_in[6];
    const float* brel2  = (const float*)d_in[7];
    const float* Wroot2 = (const float*)d_in[8];
    float* out = (float*)d_out;

    const int E_ = in_sizes[2];          // 1600000
    const int Nn = in_sizes[0] / D;      // 100000

    // workspace layout — ~26.4 MB total (under proven 39.2 MB footprint)
    char* w = (char*)d_ws;
    size_t off = 0;
    u16*  xr     = (u16*)(w + off); off += (size_t)Nn * D * sizeof(u16);   // 12.8 MB
    int*  rowptr = (int*)(w + off); off += (size_t)(Nn + 1) * sizeof(int);
    int*  cursor = (int*)(w + off); off += (size_t)Nn * sizeof(int);
    int*  partial= (int*)(w + off); off += 1024 * sizeof(int);
    off = (off + 15) & ~(size_t)15;
    unsigned long long* pairs = (unsigned long long*)(w + off);            // 12.8 MB

    const int nchunk  = (Nn + SCAN_CHUNK - 1) / SCAN_CHUNK;
    const int eBlocks = (E_ + 255) / 256;
    const int gemmBlocks   = (Nn + GW * GR - 1) / (GW * GR);
    const int gatherBlocks = (Nn + AW - 1) / AW;

    // ---- CSR build (reused by both layers) ----
    (void)hipMemsetAsync(cursor, 0, (size_t)Nn * sizeof(int), stream);
    hist_kernel<<<eBlocks, 256, 0, stream>>>(ei, cursor, E_);
    scan1_kernel<<<nchunk, 256, 0, stream>>>(cursor, rowptr, partial, Nn);
    scan2_kernel<<<1, 1024, 0, stream>>>(partial, nchunk);
    scan3_kernel<<<(Nn + 255) / 256, 256, 0, stream>>>(rowptr, partial, cursor, Nn, E_);
    fill_kernel<<<eBlocks, 256, 0, stream>>>(ei, ew, cursor, pairs, E_);

    // ---- layer 1: out = x@Wroot1^T+b1;  out = relu(gather(xr1) + out) ----
    gemm_kernel<<<gemmBlocks, 512, 0, stream>>>(x, Wrel1, brel1, Wroot1, xr, out, Nn);
    gather_kernel<true><<<gatherBlocks, 512, 0, stream>>>(xr, (const uint64_t*)pairs, rowptr, out, Nn);

    // ---- layer 2: xr2 = h@Wrel2^T; out = h@Wroot2^T+b2 (in place);  out += gather(xr2) ----
    gemm_kernel<<<gemmBlocks, 512, 0, stream>>>(out, Wrel2, brel2, Wroot2, xr, out, Nn);
    gather_kernel<false><<<gatherBlocks, 512, 0, stream>>>(xr, (const uint64_t*)pairs, rowptr, out, Nn);
}

// Round 12
// 370.813 us; speedup vs baseline: 1.1249x; 1.1249x over previous
//
#include <hip/hip_runtime.h>
#include <hip/hip_bf16.h>
#include <stdint.h>

// GraphConv x2 — round 12: round-10 passing base (fastest fill variant:
// relaxed __hip_atomic_store) + ILP-16 gather (one load volley covers a
// typical deg~16 row; padded lanes read hot row 0 with w=0).
//   CSR by dst (proven). Per layer:
//     gemm:   xr = x @ Wrel^T (bf16);  io = x @ Wroot^T + b  (io==d_out, f32)
//     gather: io[i] = [relu]( sum_j w_j * xr[src_j] + io[i] )  in place
// N=100000, E=1600000, D=64

#define D 64
#define SCAN_CHUNK 1024

typedef unsigned int   u32;
typedef unsigned short u16;

__device__ __forceinline__ float bf2f(u16 v) {
    return __uint_as_float(((u32)v) << 16);
}
__device__ __forceinline__ u16 f2bf(float f) {
    u32 u = __float_as_uint(f);
    u32 r = (u + 0x7fffu + ((u >> 16) & 1u)) >> 16;   // round-to-nearest-even
    return (u16)r;
}

// ---------------- CSR build (round-10 verbatim, proven) ----------------
__global__ __launch_bounds__(256) void hist_kernel(
    const int* __restrict__ ei, int* __restrict__ deg, int E_)
{
    int e = blockIdx.x * 256 + threadIdx.x;
    if (e >= E_) return;
    atomicAdd(&deg[ei[E_ + e]], 1);
}

__global__ __launch_bounds__(256) void scan1_kernel(
    const int* __restrict__ deg, int* __restrict__ loc, int* __restrict__ partial, int n)
{
    __shared__ int wsum[4];
    int t = threadIdx.x;
    int base = blockIdx.x * SCAN_CHUNK + t * 4;
    int v0 = (base + 0 < n) ? deg[base + 0] : 0;
    int v1 = (base + 1 < n) ? deg[base + 1] : 0;
    int v2 = (base + 2 < n) ? deg[base + 2] : 0;
    int v3 = (base + 3 < n) ? deg[base + 3] : 0;
    int s = v0 + v1 + v2 + v3;
    int lane = t & 63, wave = t >> 6;
    int inc = s;
    for (int off = 1; off < 64; off <<= 1) {
        int u = __shfl_up(inc, off);
        if (lane >= off) inc += u;
    }
    if (lane == 63) wsum[wave] = inc;
    __syncthreads();
    int woff = 0;
    for (int w = 0; w < wave; ++w) woff += wsum[w];
    int ex = woff + inc - s;
    if (base + 0 < n) loc[base + 0] = ex;
    if (base + 1 < n) loc[base + 1] = ex + v0;
    if (base + 2 < n) loc[base + 2] = ex + v0 + v1;
    if (base + 3 < n) loc[base + 3] = ex + v0 + v1 + v2;
    if (t == 255) partial[blockIdx.x] = woff + inc;
}

__global__ __launch_bounds__(1024) void scan2_kernel(int* __restrict__ partial, int nchunk)
{
    __shared__ int sd[1024];
    int t = threadIdx.x;
    if (t < nchunk) sd[t] = partial[t];
    __syncthreads();
    if (t == 0) {
        int run = 0;
        for (int i = 0; i < nchunk; ++i) { int v = sd[i]; sd[i] = run; run += v; }
    }
    __syncthreads();
    if (t < nchunk) partial[t] = sd[t];
}

__global__ __launch_bounds__(256) void scan3_kernel(
    int* __restrict__ rowptr, const int* __restrict__ partial,
    int* __restrict__ cursor, int n, int Etot)
{
    int i = blockIdx.x * 256 + threadIdx.x;
    if (i == 0) rowptr[n] = Etot;
    if (i >= n) return;
    int v = rowptr[i] + partial[i >> 10];
    rowptr[i] = v;
    cursor[i] = v;
}

__global__ __launch_bounds__(256) void fill_kernel(
    const int* __restrict__ ei, const float* __restrict__ ew,
    int* __restrict__ cursor, uint64_t* __restrict__ pairs, int E_)
{
    int e = blockIdx.x * 256 + threadIdx.x;
    if (e >= E_) return;
    int src = ei[e];
    int dst = ei[E_ + e];
    int p = atomicAdd(&cursor[dst], 1);
    // low word = src, high word = weight bits (== float2{src_as_float, w} layout)
    uint64_t packed = (uint64_t)(u32)src | ((uint64_t)__float_as_uint(ew[e]) << 32);
    // fastest measured variant (r10: 97us vs plain 120 / nt 125 / atomicExch 146)
    __hip_atomic_store(&pairs[p], packed, __ATOMIC_RELAXED, __HIP_MEMORY_SCOPE_SYSTEM);
}

// ---------------- pre-transform GEMM (round-6/9/10 proven; bf16 xr store) ----------------
// xr[i] = xin[i] @ Wrel^T (bf16);  io[i] = xin[i] @ Wroot^T + b (f32).
// xin MAY ALIAS io (layer 2) — each row read before same-row write, same wave.
#define GW 8   // waves/block (512 threads)
#define GR 4   // rows/wave
__global__ __launch_bounds__(512) void gemm_kernel(
    const float* xin,
    const float* __restrict__ Wrel, const float* __restrict__ brel,
    const float* __restrict__ Wroot,
    u16* __restrict__ xr, float* io, int Nn)
{
    __shared__ float WrelT[D][D + 1];   // WrelT[k][d] = Wrel[d*64+k]; pad kills conflicts
    __shared__ float WrootT[D][D + 1];
    __shared__ float bias[D];
    __shared__ float rowX[GW][GR][D];

    int tid = threadIdx.x;
    for (int i = tid; i < D * D; i += 512) {
        int d = i >> 6, k = i & 63;
        WrelT [k][d] = Wrel [i];
        WrootT[k][d] = Wroot[i];
    }
    if (tid < D) bias[tid] = brel[tid];
    __syncthreads();

    int wave = tid >> 6, lane = tid & 63;

    int base = (blockIdx.x * GW + wave) * GR;
    if (base >= Nn) return;             // wave-uniform, after barrier
    int nr = min(GR, Nn - base);

    for (int r = 0; r < nr; ++r)
        rowX[wave][r][lane] = xin[(size_t)(base + r) * D + lane];
    // same-wave LDS write->read (proven rounds 2/5/6/9/10)

    float aR[GR] = {0.f, 0.f, 0.f, 0.f};
    float aC[GR] = {0.f, 0.f, 0.f, 0.f};
#pragma unroll
    for (int k4 = 0; k4 < 16; ++k4) {
        float4 xv[GR];
#pragma unroll
        for (int r = 0; r < GR; ++r)
            xv[r] = *reinterpret_cast<const float4*>(&rowX[wave][r][k4 * 4]); // broadcast b128
#pragma unroll
        for (int kk = 0; kk < 4; ++kk) {
            float wr = WrelT [k4 * 4 + kk][lane];
            float wc = WrootT[k4 * 4 + kk][lane];
#pragma unroll
            for (int r = 0; r < GR; ++r) {
                float xk = (kk == 0) ? xv[r].x : (kk == 1) ? xv[r].y
                         : (kk == 2) ? xv[r].z : xv[r].w;
                aR[r] = fmaf(xk, wr, aR[r]);
                aC[r] = fmaf(xk, wc, aC[r]);
            }
        }
    }
    for (int r = 0; r < nr; ++r) {
        size_t o = (size_t)(base + r) * D + lane;
        xr[o] = f2bf(aR[r]);            // bf16 store (proven numerics)
        io[o] = aC[r] + bias[lane];
    }
}

// ---------------- gather: ILP-16, bf16 rows, zero-weight padded ----------------
#define AW 8
template <bool RELU>
__global__ __launch_bounds__(512) void gather_kernel(
    const u16* __restrict__ xr, const uint64_t* __restrict__ pairs,
    const int* __restrict__ rowptr, float* __restrict__ io, int Nn)
{
    int tid  = threadIdx.x;
    int wave = tid >> 6, lane = tid & 63;
    int i = blockIdx.x * AW + wave;
    if (i >= Nn) return;                       // wave-uniform

    int beg = rowptr[i], end = rowptr[i + 1];
    float acc = 0.f;
    for (int b = beg; b < end; b += 64) {
        int cnt = min(64, end - b);
        // lanes >= cnt carry (src=0, w=0): padded edges read row 0, add 0
        uint64_t pv = (lane < cnt) ? __builtin_nontemporal_load(&pairs[b + lane])
                                   : (uint64_t)0;
        int   ps = (int)(u32)pv;
        float wv = __uint_as_float((u32)(pv >> 32));
        for (int j = 0; j < cnt; j += 16) {    // 16 independent gathers in flight
            int s0  = __shfl(ps, j + 0),  s1  = __shfl(ps, j + 1);
            int s2  = __shfl(ps, j + 2),  s3  = __shfl(ps, j + 3);
            int s4  = __shfl(ps, j + 4),  s5  = __shfl(ps, j + 5);
            int s6  = __shfl(ps, j + 6),  s7  = __shfl(ps, j + 7);
            int s8  = __shfl(ps, j + 8),  s9  = __shfl(ps, j + 9);
            int s10 = __shfl(ps, j + 10), s11 = __shfl(ps, j + 11);
            int s12 = __shfl(ps, j + 12), s13 = __shfl(ps, j + 13);
            int s14 = __shfl(ps, j + 14), s15 = __shfl(ps, j + 15);
            float w0  = __shfl(wv, j + 0),  w1  = __shfl(wv, j + 1);
            float w2  = __shfl(wv, j + 2),  w3  = __shfl(wv, j + 3);
            float w4  = __shfl(wv, j + 4),  w5  = __shfl(wv, j + 5);
            float w6  = __shfl(wv, j + 6),  w7  = __shfl(wv, j + 7);
            float w8  = __shfl(wv, j + 8),  w9  = __shfl(wv, j + 9);
            float w10 = __shfl(wv, j + 10), w11 = __shfl(wv, j + 11);
            float w12 = __shfl(wv, j + 12), w13 = __shfl(wv, j + 13);
            float w14 = __shfl(wv, j + 14), w15 = __shfl(wv, j + 15);
            float v0  = bf2f(xr[(size_t)s0  * D + lane]);
            float v1  = bf2f(xr[(size_t)s1  * D + lane]);
            float v2  = bf2f(xr[(size_t)s2  * D + lane]);
            float v3  = bf2f(xr[(size_t)s3  * D + lane]);
            float v4  = bf2f(xr[(size_t)s4  * D + lane]);
            float v5  = bf2f(xr[(size_t)s5  * D + lane]);
            float v6  = bf2f(xr[(size_t)s6  * D + lane]);
            float v7  = bf2f(xr[(size_t)s7  * D + lane]);
            float v8  = bf2f(xr[(size_t)s8  * D + lane]);
            float v9  = bf2f(xr[(size_t)s9  * D + lane]);
            float v10 = bf2f(xr[(size_t)s10 * D + lane]);
            float v11 = bf2f(xr[(size_t)s11 * D + lane]);
            float v12 = bf2f(xr[(size_t)s12 * D + lane]);
            float v13 = bf2f(xr[(size_t)s13 * D + lane]);
            float v14 = bf2f(xr[(size_t)s14 * D + lane]);
            float v15 = bf2f(xr[(size_t)s15 * D + lane]);
            acc = fmaf(v0,  w0,  acc); acc = fmaf(v1,  w1,  acc);
            acc = fmaf(v2,  w2,  acc); acc = fmaf(v3,  w3,  acc);
            acc = fmaf(v4,  w4,  acc); acc = fmaf(v5,  w5,  acc);
            acc = fmaf(v6,  w6,  acc); acc = fmaf(v7,  w7,  acc);
            acc = fmaf(v8,  w8,  acc); acc = fmaf(v9,  w9,  acc);
            acc = fmaf(v10, w10, acc); acc = fmaf(v11, w11, acc);
            acc = fmaf(v12, w12, acc); acc = fmaf(v13, w13, acc);
            acc = fmaf(v14, w14, acc); acc = fmaf(v15, w15, acc);
        }
    }
    size_t o = (size_t)i * D + lane;
    float v = acc + io[o];
    io[o] = RELU ? fmaxf(v, 0.f) : v;
}

extern "C" void kernel_launch(void* const* d_in, const int* in_sizes, int n_in,
                              void* d_out, int out_size, void* d_ws, size_t ws_size,
                              hipStream_t stream)
{
    const float* x      = (const float*)d_in[0];
    const int*   ei     = (const int*)  d_in[1];
    const float* ew     = (const float*)d_in[2];
    const float* Wrel1  = (const float*)d_in[3];
    const float* brel1  = (const float*)d_in[4];
    const float* Wroot1 = (const float*)d_in[5];
    const float* Wrel2  = (const float*)d_in[6];
    const float* brel2  = (const float*)d_in[7];
    const float* Wroot2 = (const float*)d_in[8];
    float* out = (float*)d_out;

    const int E_ = in_sizes[2];          // 1600000
    const int Nn = in_sizes[0] / D;      // 100000

    // workspace layout — ~26.4 MB total (under proven 39.2 MB footprint)
    char* w = (char*)d_ws;
    size_t off = 0;
    u16*  xr     = (u16*)(w + off); off += (size_t)Nn * D * sizeof(u16);   // 12.8 MB
    int*  rowptr = (int*)(w + off); off += (size_t)(Nn + 1) * sizeof(int);
    int*  cursor = (int*)(w + off); off += (size_t)Nn * sizeof(int);
    int*  partial= (int*)(w + off); off += 1024 * sizeof(int);
    off = (off + 15) & ~(size_t)15;
    uint64_t* pairs = (uint64_t*)(w + off);                                // 12.8 MB

    const int nchunk  = (Nn + SCAN_CHUNK - 1) / SCAN_CHUNK;
    const int eBlocks = (E_ + 255) / 256;
    const int gemmBlocks   = (Nn + GW * GR - 1) / (GW * GR);
    const int gatherBlocks = (Nn + AW - 1) / AW;

    // ---- CSR build (reused by both layers) ----
    (void)hipMemsetAsync(cursor, 0, (size_t)Nn * sizeof(int), stream);
    hist_kernel<<<eBlocks, 256, 0, stream>>>(ei, cursor, E_);
    scan1_kernel<<<nchunk, 256, 0, stream>>>(cursor, rowptr, partial, Nn);
    scan2_kernel<<<1, 1024, 0, stream>>>(partial, nchunk);
    scan3_kernel<<<(Nn + 255) / 256, 256, 0, stream>>>(rowptr, partial, cursor, Nn, E_);
    fill_kernel<<<eBlocks, 256, 0, stream>>>(ei, ew, cursor, pairs, E_);

    // ---- layer 1: out = x@Wroot1^T+b1;  out = relu(gather(xr1) + out) ----
    gemm_kernel<<<gemmBlocks, 512, 0, stream>>>(x, Wrel1, brel1, Wroot1, xr, out, Nn);
    gather_kernel<true><<<gatherBlocks, 512, 0, stream>>>(xr, pairs, rowptr, out, Nn);

    // ---- layer 2: xr2 = h@Wrel2^T; out = h@Wroot2^T+b2 (in place);  out += gather(xr2) ----
    gemm_kernel<<<gemmBlocks, 512, 0, stream>>>(out, Wrel2, brel2, Wroot2, xr, out, Nn);
    gather_kernel<false><<<gatherBlocks, 512, 0, stream>>>(xr, pairs, rowptr, out, Nn);
}